// Round 10
// baseline (94.880 us; speedup 1.0000x reference)
//
#include <hip/hip_runtime.h>
#include <hip/hip_bf16.h>

#define B_ROWS 4096
#define N2 8192
#define DD 512
#define NB 64        // 8192/128 tile-blocks per dim
#define NTRI 2080    // NB*(NB+1)/2
#define NTK 4        // DD/128 K-tiles (fp8: BK=128)

typedef __attribute__((ext_vector_type(4))) float float4v;
typedef __attribute__((ext_vector_type(2))) long long2v;

// ---------- normalize + targets + rowsum-zero, one wave per row-pair ----------
// Outputs zn as fp8 e4m3 (OCP), 512 B per row. Zeroes all 8 rowsum copies.
__global__ __launch_bounds__(256) void k_norm_tgt(const float* __restrict__ f1,
                                                  const float* __restrict__ f2,
                                                  unsigned char* __restrict__ zn8,
                                                  float* __restrict__ tpart,
                                                  float* __restrict__ rowsum) {
  int w = threadIdx.x >> 6, lane = threadIdx.x & 63;
  int j = blockIdx.x * 4 + w;  // pair index 0..4095
  const float4* s1 = (const float4*)(f1 + (size_t)j * DD);
  const float4* s2 = (const float4*)(f2 + (size_t)j * DD);
  float4 a0 = s1[lane * 2], a1 = s1[lane * 2 + 1];
  float4 b0 = s2[lane * 2], b1 = s2[lane * 2 + 1];
  float ss1 = a0.x * a0.x + a0.y * a0.y + a0.z * a0.z + a0.w * a0.w +
              a1.x * a1.x + a1.y * a1.y + a1.z * a1.z + a1.w * a1.w;
  float ss2 = b0.x * b0.x + b0.y * b0.y + b0.z * b0.z + b0.w * b0.w +
              b1.x * b1.x + b1.y * b1.y + b1.z * b1.z + b1.w * b1.w;
  float ab = a0.x * b0.x + a0.y * b0.y + a0.z * b0.z + a0.w * b0.w +
             a1.x * b1.x + a1.y * b1.y + a1.z * b1.z + a1.w * b1.w;
#pragma unroll
  for (int o = 1; o < 64; o <<= 1) {
    ss1 += __shfl_xor(ss1, o, 64);
    ss2 += __shfl_xor(ss2, o, 64);
    ab += __shfl_xor(ab, o, 64);
  }
  float inv1 = 1.0f / fmaxf(sqrtf(ss1), 1e-8f);
  float inv2 = 1.0f / fmaxf(sqrtf(ss2), 1e-8f);

  // pack 8 normalized elems -> 8 fp8 bytes (RNE via HW cvt)
  uint2 q;
  int lo = __builtin_amdgcn_cvt_pk_fp8_f32(a0.x * inv1, a0.y * inv1, 0, false);
  lo = __builtin_amdgcn_cvt_pk_fp8_f32(a0.z * inv1, a0.w * inv1, lo, true);
  q.x = (unsigned int)lo;
  lo = __builtin_amdgcn_cvt_pk_fp8_f32(a1.x * inv1, a1.y * inv1, 0, false);
  lo = __builtin_amdgcn_cvt_pk_fp8_f32(a1.z * inv1, a1.w * inv1, lo, true);
  q.y = (unsigned int)lo;
  ((uint2*)(zn8 + (size_t)j * DD))[lane] = q;

  lo = __builtin_amdgcn_cvt_pk_fp8_f32(b0.x * inv2, b0.y * inv2, 0, false);
  lo = __builtin_amdgcn_cvt_pk_fp8_f32(b0.z * inv2, b0.w * inv2, lo, true);
  q.x = (unsigned int)lo;
  lo = __builtin_amdgcn_cvt_pk_fp8_f32(b1.x * inv2, b1.y * inv2, 0, false);
  lo = __builtin_amdgcn_cvt_pk_fp8_f32(b1.z * inv2, b1.w * inv2, lo, true);
  q.y = (unsigned int)lo;
  ((uint2*)(zn8 + (size_t)(B_ROWS + j) * DD))[lane] = q;

  if (lane == 0) tpart[j] = 2.0f + 2.0f * ab * inv1 * inv2;  // fp32-exact target terms
  // zero 8 XCD-local rowsum copies: 8*8192 floats over 1024 blocks
  if (threadIdx.x < 64) rowsum[blockIdx.x * 64 + threadIdx.x] = 0.f;
}

// ---------- main: upper-triangular 128x128 tiles of S = zn.zn^T (fp8 MFMA) ----------
// Band-major order (L2-resident B window) + XCD-chunked swizzle.
// Single-buffer 32KB LDS -> 5 blocks/CU; BK=128; b128 frag reads (conflict-free);
// atomics go to an XCD-local rowsum copy (no cross-XCD line ping-pong).
__global__ __launch_bounds__(256, 5) void k_gemm_expsum(const unsigned char* __restrict__ zn8,
                                                        float* __restrict__ rowsum) {
  __shared__ __align__(16) char smem[32768];  // [A 16KB | B 16KB], single buffer

  // XCD-chunked swizzle (2080 % 8 == 0): each XCD gets a contiguous band-major range
  int g = (blockIdx.x & 7) * (NTRI / 8) + (blockIdx.x >> 3);
  float* rs = rowsum + (size_t)(blockIdx.x & 7) * N2;  // XCD-local copy

  // band-major decode: band b covers bj in [8b, 8b+8), bi in [0, bj].
  int b = 7;
  while (32 * b * b + 4 * b > g) --b;
  int tp = g - (32 * b * b + 4 * b);
  int bi, bj;
  if (tp < 64 * b) {
    bi = tp >> 3;                 // A panel reused for 8 consecutive tiles
    bj = 8 * b + (tp & 7);        // B window: 8 panels (512 KB), L2-hot
  } else {
    int u = tp - 64 * b;          // 0..35: upper-tri of the 8x8 diagonal block
    int r = 0;
    while ((r + 1) * 8 - (r * (r + 1)) / 2 <= u) ++r;
    int before = r * 8 - ((r - 1) * r) / 2;
    bi = 8 * b + r;
    bj = 8 * b + r + (u - before);
  }

  const int tid = threadIdx.x;
  const int lane = tid & 63, w = tid >> 6;
  const int wr = w >> 1, wc = w & 1;
  const int lr = lane & 15;
  const char* zb = (const char*)zn8;
  const int arow0 = bi * 128, brow0 = bj * 128;

  // staging geometry: 4 chunks/thread per 16KB op-tile; linear LDS dest,
  // inverse-swizzled global source (rule #21). Rows are 128 B (128 fp8).
  int srow[4], scol[4];
#pragma unroll
  for (int cc = 0; cc < 4; ++cc) {
    int lo = cc * 4096 + w * 1024 + lane * 16;     // linear LDS byte offset
    srow[cc] = lo >> 7;                            // tile row (128 B/row)
    scol[cc] = (lo & 127) ^ ((srow[cc] & 7) << 4); // 16B-granular XOR swizzle
  }

  float4v acc[4][4];
#pragma unroll
  for (int m = 0; m < 4; ++m)
#pragma unroll
    for (int n = 0; n < 4; ++n) acc[m][n] = {0.f, 0.f, 0.f, 0.f};

  for (int t = 0; t < NTK; ++t) {
    // stage tile t (A+B): 8 x global_load_lds width-16 per thread
#pragma unroll
    for (int cc = 0; cc < 4; ++cc) {
      const char* ga = zb + (size_t)(arow0 + srow[cc]) * DD + t * 128 + scol[cc];
      const char* gb = zb + (size_t)(brow0 + srow[cc]) * DD + t * 128 + scol[cc];
      __builtin_amdgcn_global_load_lds((__attribute__((address_space(1))) void*)ga,
          (__attribute__((address_space(3))) void*)(smem + cc * 4096 + w * 1024), 16, 0, 0);
      __builtin_amdgcn_global_load_lds((__attribute__((address_space(1))) void*)gb,
          (__attribute__((address_space(3))) void*)(smem + 16384 + cc * 4096 + w * 1024), 16, 0, 0);
    }
    __syncthreads();  // drains vmcnt; latency hidden by other resident blocks

    const char* ab = smem;
    const char* bb = smem + 16384;
#pragma unroll
    for (int kk = 0; kk < 2; ++kk) {
      long2v a[4], bq[4];
      int ko = kk * 64 + ((lane >> 4) << 4);  // 16 fp8 = 2 MFMA k-chunks per read
#pragma unroll
      for (int m = 0; m < 4; ++m) {
        int row = wr * 64 + m * 16 + lr;
        a[m] = *(const long2v*)(ab + row * 128 + (ko ^ ((row & 7) << 4)));
      }
#pragma unroll
      for (int n = 0; n < 4; ++n) {
        int row = wc * 64 + n * 16 + lr;
        bq[n] = *(const long2v*)(bb + row * 128 + (ko ^ ((row & 7) << 4)));
      }
#pragma unroll
      for (int m = 0; m < 4; ++m)
#pragma unroll
        for (int n = 0; n < 4; ++n) {
          acc[m][n] = __builtin_amdgcn_mfma_f32_16x16x32_fp8_fp8(a[m][0], bq[n][0], acc[m][n], 0, 0, 0);
          acc[m][n] = __builtin_amdgcn_mfma_f32_16x16x32_fp8_fp8(a[m][1], bq[n][1], acc[m][n], 0, 0, 0);
        }
    }
    if (t + 1 < NTK) __syncthreads();  // all reads done before next stage overwrites
  }

  // epilogue: e = exp(2*dot - 2) = exp2(C*dot - C)
  const float C = 2.88539008177792681f;
  float rowacc[4][4];
  float colacc[4] = {0.f, 0.f, 0.f, 0.f};
#pragma unroll
  for (int m = 0; m < 4; ++m)
#pragma unroll
    for (int r = 0; r < 4; ++r) rowacc[m][r] = 0.f;
#pragma unroll
  for (int m = 0; m < 4; ++m)
#pragma unroll
    for (int n = 0; n < 4; ++n)
#pragma unroll
      for (int r = 0; r < 4; ++r) {
        float e = exp2f(fmaf(acc[m][n][r], C, -C));
        rowacc[m][r] += e;
        colacc[n] += e;
      }

  // row sums: reduce over columns (lane&15); one atomic per row per wave
#pragma unroll
  for (int m = 0; m < 4; ++m)
#pragma unroll
    for (int r = 0; r < 4; ++r) {
      float v = rowacc[m][r];
      v += __shfl_xor(v, 1);
      v += __shfl_xor(v, 2);
      v += __shfl_xor(v, 4);
      v += __shfl_xor(v, 8);
      if ((lane & 15) == 0)
        atomicAdd(&rs[arow0 + wr * 64 + m * 16 + ((lane >> 4) << 2) + r], v);
    }
  // col sums (symmetric contribution), off-diagonal tiles only
  if (bi != bj) {
#pragma unroll
    for (int n = 0; n < 4; ++n) {
      float v = colacc[n];
      v += __shfl_xor(v, 16);
      v += __shfl_xor(v, 32);
      if (lane < 16) atomicAdd(&rs[brow0 + wc * 64 + n * 16 + lane], v);
    }
  }
}

// ---------- finalize: loss = (sum(2 + log sum_x rowsum[x][i]) - sum tpart) / 8192 ----------
__global__ __launch_bounds__(256) void k_finalize(const float* __restrict__ rowsum,
                                                  const float* __restrict__ tpart,
                                                  float* __restrict__ out) {
  int t = threadIdx.x;
  float acc = 0.f;
  for (int i = t; i < N2; i += 256) {
    float s = 0.f;
#pragma unroll
    for (int x = 0; x < 8; ++x) s += rowsum[x * N2 + i];
    acc += 2.0f + logf(s);
  }
  for (int i = t; i < B_ROWS; i += 256) acc -= tpart[i];
#pragma unroll
  for (int off = 32; off; off >>= 1) acc += __shfl_down(acc, off, 64);
  __shared__ float wsum[4];
  if ((t & 63) == 0) wsum[t >> 6] = acc;
  __syncthreads();
  if (t == 0) out[0] = (wsum[0] + wsum[1] + wsum[2] + wsum[3]) * (1.0f / (float)N2);
}

extern "C" void kernel_launch(void* const* d_in, const int* in_sizes, int n_in,
                              void* d_out, int out_size, void* d_ws, size_t ws_size,
                              hipStream_t stream) {
  const float* f1 = (const float*)d_in[0];
  const float* f2 = (const float*)d_in[1];
  float* out = (float*)d_out;
  char* ws = (char*)d_ws;

  unsigned char* zn8 = (unsigned char*)ws;               // 8192*512 = 4 MB fp8
  float* rowsum = (float*)(ws + (size_t)N2 * DD);        // 8 copies x 32 KB
  float* tpart = rowsum + 8 * N2;                        // 16 KB

  k_norm_tgt<<<B_ROWS / 4, 256, 0, stream>>>(f1, f2, zn8, tpart, rowsum);
  k_gemm_expsum<<<NTRI, 256, 0, stream>>>(zn8, rowsum);
  k_finalize<<<1, 256, 0, stream>>>(rowsum, tpart, out);
}

// Round 11
// 63.216 us; speedup vs baseline: 1.5009x; 1.5009x over previous
//
#include <hip/hip_runtime.h>
#include <hip/hip_bf16.h>

#define B_ROWS 4096
#define N2 8192
#define DD 512
#define NBLK 544   // sum over P of ceil((128-2P)/8)

typedef __attribute__((ext_vector_type(4))) float float4v;
typedef __attribute__((ext_vector_type(2))) long long2v;

// ---------- normalize + targets + rowsum-zero, one wave per row-pair ----------
// Outputs zn as fp8 e4m3 (OCP), 512 B per row.
__global__ __launch_bounds__(256) void k_norm_tgt(const float* __restrict__ f1,
                                                  const float* __restrict__ f2,
                                                  unsigned char* __restrict__ zn8,
                                                  float* __restrict__ tpart,
                                                  float* __restrict__ rowsum) {
  int w = threadIdx.x >> 6, lane = threadIdx.x & 63;
  int j = blockIdx.x * 4 + w;  // pair index 0..4095
  const float4* s1 = (const float4*)(f1 + (size_t)j * DD);
  const float4* s2 = (const float4*)(f2 + (size_t)j * DD);
  float4 a0 = s1[lane * 2], a1 = s1[lane * 2 + 1];
  float4 b0 = s2[lane * 2], b1 = s2[lane * 2 + 1];
  float ss1 = a0.x * a0.x + a0.y * a0.y + a0.z * a0.z + a0.w * a0.w +
              a1.x * a1.x + a1.y * a1.y + a1.z * a1.z + a1.w * a1.w;
  float ss2 = b0.x * b0.x + b0.y * b0.y + b0.z * b0.z + b0.w * b0.w +
              b1.x * b1.x + b1.y * b1.y + b1.z * b1.z + b1.w * b1.w;
  float ab = a0.x * b0.x + a0.y * b0.y + a0.z * b0.z + a0.w * b0.w +
             a1.x * b1.x + a1.y * b1.y + a1.z * b1.z + a1.w * b1.w;
#pragma unroll
  for (int o = 1; o < 64; o <<= 1) {
    ss1 += __shfl_xor(ss1, o, 64);
    ss2 += __shfl_xor(ss2, o, 64);
    ab += __shfl_xor(ab, o, 64);
  }
  float inv1 = 1.0f / fmaxf(sqrtf(ss1), 1e-8f);
  float inv2 = 1.0f / fmaxf(sqrtf(ss2), 1e-8f);

  uint2 q;
  int lo = __builtin_amdgcn_cvt_pk_fp8_f32(a0.x * inv1, a0.y * inv1, 0, false);
  lo = __builtin_amdgcn_cvt_pk_fp8_f32(a0.z * inv1, a0.w * inv1, lo, true);
  q.x = (unsigned int)lo;
  lo = __builtin_amdgcn_cvt_pk_fp8_f32(a1.x * inv1, a1.y * inv1, 0, false);
  lo = __builtin_amdgcn_cvt_pk_fp8_f32(a1.z * inv1, a1.w * inv1, lo, true);
  q.y = (unsigned int)lo;
  ((uint2*)(zn8 + (size_t)j * DD))[lane] = q;

  lo = __builtin_amdgcn_cvt_pk_fp8_f32(b0.x * inv2, b0.y * inv2, 0, false);
  lo = __builtin_amdgcn_cvt_pk_fp8_f32(b0.z * inv2, b0.w * inv2, lo, true);
  q.x = (unsigned int)lo;
  lo = __builtin_amdgcn_cvt_pk_fp8_f32(b1.x * inv2, b1.y * inv2, 0, false);
  lo = __builtin_amdgcn_cvt_pk_fp8_f32(b1.z * inv2, b1.w * inv2, lo, true);
  q.y = (unsigned int)lo;
  ((uint2*)(zn8 + (size_t)(B_ROWS + j) * DD))[lane] = q;

  if (lane == 0) tpart[j] = 2.0f + 2.0f * ab * inv1 * inv2;  // fp32-exact target terms
  if (threadIdx.x < 8) rowsum[blockIdx.x * 8 + threadIdx.x] = 0.f;  // 1024*8 = 8192
}

// ---------- main: persistent-A fp8 GEMM + exp-rowsum ----------
// Block = 128 rows (A fully in registers, full K), loops over <=8 B-panels
// (64 cols x 512 K, 32 KB LDS, double-buffered, counted vmcnt).
// Tiles (P, j) for j >= 2P; mirror col-sums only for j >= 2P+2 (exactly-once).
__global__ __launch_bounds__(256, 2) void k_gemm_expsum(const unsigned char* __restrict__ zn8,
                                                        float* __restrict__ rowsum) {
  __shared__ __align__(16) char bbuf[2][32768];
  __shared__ float scratch[4][64];
  __shared__ float colaccum[512];

  // XCD-chunked bijective swizzle (544 = 8*68); order stays big-blocks-first
  int g = (blockIdx.x & 7) * (NBLK / 8) + (blockIdx.x >> 3);

  // decode (P, chunk)
  int P = 0, off = 0;
  for (;;) {
    int nb = (128 - 2 * P + 7) >> 3;
    if (g < off + nb) break;
    off += nb;
    ++P;
  }
  int c = g - off;
  int j0 = 2 * P + 8 * c;
  int nt = 128 - j0; if (nt > 8) nt = 8;
  const int jmir0 = 2 * P + 2;  // j >= jmir0 -> add mirror col-sums

  const int tid = threadIdx.x;
  const int lane = tid & 63, w = tid >> 6;
  const int lr = lane & 15, hi2 = lane >> 4;
  const char* zb = (const char*)zn8;
  const int arow0 = P * 128;

  colaccum[tid] = 0.f;
  colaccum[tid + 256] = 0.f;

  // stage geometry: 64-row x 512B panel -> 32KB buf; linear LDS dest,
  // inverse-swizzled global source (swizzle cancels on read -> exact bytes)
  int srow[8], scol[8];
#pragma unroll
  for (int cc = 0; cc < 8; ++cc) {
    int lo2 = cc * 4096 + tid * 16;
    srow[cc] = lo2 >> 9;
    scol[cc] = (lo2 & 511) ^ ((srow[cc] & 7) << 4);
  }

#define STAGE(bufp, rowbase) do {                                                        \
    _Pragma("unroll")                                                                    \
    for (int cc = 0; cc < 8; ++cc) {                                                     \
      const char* _s = zb + (size_t)((rowbase) + srow[cc]) * DD + scol[cc];              \
      __builtin_amdgcn_global_load_lds((__attribute__((address_space(1))) void*)_s,      \
          (__attribute__((address_space(3))) void*)((bufp) + cc * 4096 + (w << 10)), 16, 0, 0); \
    }                                                                                    \
  } while (0)

  // ---- load A panel (128 rows x 512 K fp8) into registers via LDS ----
  STAGE((char*)bbuf[0], arow0);        // rows 0-63
  STAGE((char*)bbuf[1], arow0 + 64);   // rows 64-127
  asm volatile("s_waitcnt vmcnt(0)" ::: "memory");
  __builtin_amdgcn_sched_barrier(0);
  __builtin_amdgcn_s_barrier();

  long2v aR[2][8];  // 64 VGPR: rows 32w+16m+lr, k-window p*64+hi2*16 (16B)
  {
    const char* base = (const char*)bbuf[w >> 1];
#pragma unroll
    for (int m = 0; m < 2; ++m) {
      int rr = ((w & 1) << 5) + (m << 4) + lr;
      const char* rowp = base + rr * DD;
      int sz = (rr & 7) << 4;
#pragma unroll
      for (int p = 0; p < 8; ++p)
        aR[m][p] = *(const long2v*)(rowp + ((p * 64 + hi2 * 16) ^ sz));
    }
  }
  asm volatile("s_waitcnt lgkmcnt(0)" ::: "memory");
  __builtin_amdgcn_sched_barrier(0);
  __builtin_amdgcn_s_barrier();  // all waves done reading A; bufs free for B

  float rowacc[2][4];
#pragma unroll
  for (int m = 0; m < 2; ++m)
#pragma unroll
    for (int r = 0; r < 4; ++r) rowacc[m][r] = 0.f;

  STAGE((char*)bbuf[0], j0 * 64);  // B tile 0

  for (int t = 0; t < nt; ++t) {
    if (t + 1 < nt) {
      STAGE((char*)bbuf[(t + 1) & 1], (j0 + t + 1) * 64);
      asm volatile("s_waitcnt vmcnt(8)" ::: "memory");  // tile t landed, t+1 in flight
    } else {
      asm volatile("s_waitcnt vmcnt(0)" ::: "memory");
    }
    __builtin_amdgcn_sched_barrier(0);
    __builtin_amdgcn_s_barrier();

    const char* bb = (const char*)bbuf[t & 1];
    float4v acc[2][4];
#pragma unroll
    for (int m = 0; m < 2; ++m)
#pragma unroll
      for (int n = 0; n < 4; ++n) acc[m][n] = {0.f, 0.f, 0.f, 0.f};

#pragma unroll
    for (int n = 0; n < 4; ++n) {
      long2v bR[8];
      int col = (n << 4) + lr;
      const char* colp = bb + col * DD;
      int sz = (col & 7) << 4;
#pragma unroll
      for (int p = 0; p < 8; ++p)
        bR[p] = *(const long2v*)(colp + ((p * 64 + hi2 * 16) ^ sz));
#pragma unroll
      for (int p = 0; p < 8; ++p)
#pragma unroll
        for (int m = 0; m < 2; ++m) {
          acc[m][n] = __builtin_amdgcn_mfma_f32_16x16x32_fp8_fp8(aR[m][p][0], bR[p][0], acc[m][n], 0, 0, 0);
          acc[m][n] = __builtin_amdgcn_mfma_f32_16x16x32_fp8_fp8(aR[m][p][1], bR[p][1], acc[m][n], 0, 0, 0);
        }
    }

    // epilogue tile t: e = exp(2*dot - 2) = exp2(C*dot - C)
    const float C = 2.88539008177792681f;
    float colp4[4] = {0.f, 0.f, 0.f, 0.f};
#pragma unroll
    for (int m = 0; m < 2; ++m)
#pragma unroll
      for (int n = 0; n < 4; ++n)
#pragma unroll
        for (int r = 0; r < 4; ++r) {
          float e = exp2f(fmaf(acc[m][n][r], C, -C));
          rowacc[m][r] += e;   // rows accumulate across n and tiles (regs)
          colp4[n] += e;
        }
    if ((j0 + t) >= jmir0) {
#pragma unroll
      for (int n = 0; n < 4; ++n) {
        float v = colp4[n];
        v += __shfl_xor(v, 16);
        v += __shfl_xor(v, 32);
        if (hi2 == 0) scratch[w][(n << 4) + lr] = v;
      }
    } else {
      if (hi2 == 0) {
#pragma unroll
        for (int n = 0; n < 4; ++n) scratch[w][(n << 4) + lr] = 0.f;
      }
    }
    __builtin_amdgcn_s_barrier();  // scratch ready; also fences B-buf reads (dbuf safe)
    if (w == 0) {
      float s = scratch[0][lane] + scratch[1][lane] + scratch[2][lane] + scratch[3][lane];
      colaccum[t * 64 + lane] += s;
    }
  }
#undef STAGE

  // row atomics: one per row per block
#pragma unroll
  for (int m = 0; m < 2; ++m)
#pragma unroll
    for (int r = 0; r < 4; ++r) {
      float v = rowacc[m][r];
      v += __shfl_xor(v, 1);
      v += __shfl_xor(v, 2);
      v += __shfl_xor(v, 4);
      v += __shfl_xor(v, 8);
      if (lr == 0)
        atomicAdd(&rowsum[arow0 + (w << 5) + (m << 4) + (hi2 << 2) + r], v);
    }
  // col mirror atomics: flush colaccum once per block
  __builtin_amdgcn_s_barrier();
  for (int idx = tid; idx < nt * 64; idx += 256) {
    float v = colaccum[idx];
    if (v != 0.f) atomicAdd(&rowsum[(j0 + (idx >> 6)) * 64 + (idx & 63)], v);
  }
}

// ---------- finalize: loss = (sum(2 + log rowsum) - sum tpart) / 8192 ----------
__global__ __launch_bounds__(1024) void k_finalize(const float* __restrict__ rowsum,
                                                   const float* __restrict__ tpart,
                                                   float* __restrict__ out) {
  int t = threadIdx.x;
  float acc = 0.f;
  for (int i = t; i < N2; i += 1024) acc += 2.0f + logf(rowsum[i]);
  for (int i = t; i < B_ROWS; i += 1024) acc -= tpart[i];
#pragma unroll
  for (int o = 32; o; o >>= 1) acc += __shfl_down(acc, o, 64);
  __shared__ float wsum[16];
  if ((t & 63) == 0) wsum[t >> 6] = acc;
  __syncthreads();
  if (t == 0) {
    float s = 0.f;
#pragma unroll
    for (int k = 0; k < 16; ++k) s += wsum[k];
    out[0] = s * (1.0f / (float)N2);
  }
}

extern "C" void kernel_launch(void* const* d_in, const int* in_sizes, int n_in,
                              void* d_out, int out_size, void* d_ws, size_t ws_size,
                              hipStream_t stream) {
  const float* f1 = (const float*)d_in[0];
  const float* f2 = (const float*)d_in[1];
  float* out = (float*)d_out;
  char* ws = (char*)d_ws;

  unsigned char* zn8 = (unsigned char*)ws;               // 8192*512 = 4 MB fp8
  float* rowsum = (float*)(ws + (size_t)N2 * DD);        // 32 KB
  float* tpart = rowsum + N2;                            // 16 KB

  k_norm_tgt<<<B_ROWS / 4, 256, 0, stream>>>(f1, f2, zn8, tpart, rowsum);
  k_gemm_expsum<<<NBLK, 256, 0, stream>>>(zn8, rowsum);
  k_finalize<<<1, 1024, 0, stream>>>(rowsum, tpart, out);
}